// Round 2
// baseline (299.847 us; speedup 1.0000x reference)
//
#include <hip/hip_runtime.h>
#include <cstdint>

#define NROWS 16384
#define FDIM 64
#define HDIM 128
#define ODIM 512
#define KDIM 8192   // FDIM * HDIM

#define BM 256
#define BN 256
#define BK 64

typedef short bf16x8 __attribute__((ext_vector_type(8)));
typedef float f32x4 __attribute__((ext_vector_type(4)));
typedef uint32_t u32x4 __attribute__((ext_vector_type(4)));

__device__ __forceinline__ uint16_t rne_bf16(float f) {
  uint32_t u = __builtin_bit_cast(uint32_t, f);
  u += 0x7fffu + ((u >> 16) & 1u);
  return (uint16_t)(u >> 16);
}

// ---- pre-kernel 1: W2 [K=8192][O=512] f32 -> W2T [O][K] bf16 (LDS tile transpose) ----
__global__ void prep_w2t(const float* __restrict__ W2, uint16_t* __restrict__ W2T) {
  __shared__ float tile[64][65];
  const int k0 = blockIdx.x * 64;
  const int o0 = blockIdx.y * 64;
  const int tx = threadIdx.x;  // 0..63
  const int ty = threadIdx.y;  // 0..7
#pragma unroll
  for (int j = 0; j < 8; ++j)
    tile[ty + 8 * j][tx] = W2[(size_t)(k0 + ty + 8 * j) * ODIM + o0 + tx];
  __syncthreads();
#pragma unroll
  for (int j = 0; j < 8; ++j)
    W2T[(size_t)(o0 + ty + 8 * j) * KDIM + k0 + tx] = rne_bf16(tile[tx][ty + 8 * j]);
}

// ---- pre-kernel 2: b2sum[o] = sum_f b2[f][o] ----
__global__ void prep_b2sum(const float* __restrict__ b2, float* __restrict__ b2sum) {
  const int t = blockIdx.x * 256 + threadIdx.x;  // grid 2*256 = 512 = ODIM
  float s = 0.f;
#pragma unroll
  for (int f = 0; f < FDIM; ++f) s += b2[(size_t)f * ODIM + t];
  b2sum[t] = s;
}

// ---- split-K combine: out = (acc_ko0(out) + acc_ko1(p1) + b2sum) / 8 ----
__global__ void combine_out(const float* __restrict__ p1, const float* __restrict__ b2sum,
                            float* __restrict__ out) {
  const size_t i = ((size_t)blockIdx.x * 256 + threadIdx.x) * 4;
  f32x4 a = *(const f32x4*)(out + i);
  f32x4 b = *(const f32x4*)(p1 + i);
  f32x4 s = *(const f32x4*)(b2sum + (i & 511));
  *(f32x4*)(out + i) = (a + b + s) * 0.125f;
}

// ---- main fused kernel: m201 geometry. BM=BN=256, 8 waves of 128x64 wave-tiles,
// BK=64, 128 KB double-buffered LDS (statically-named buffers), split-K (KSPLIT=2).
// MACs per LDS-frag-byte = 128*64/(128+64)/2 = 21.3 (vs 16 at 64x64 tiles).
// Register operands (x/W1/b1) for step t+1 are loaded during step t (ping-pong
// RegSets, issued BEFORE the glds) so elu never waits on vmcnt mid-step.
struct RegSet {
  f32x4 w1lo, w1hi, b1lo, b1hi;
  float xv[4];
};

template <int KSPLIT>
__global__ __launch_bounds__(512, 2) void mlp_gemm(
    const float* __restrict__ x, const float* __restrict__ W1,
    const float* __restrict__ b1, const uint16_t* __restrict__ W2T,
    const float* __restrict__ b2sum, float* __restrict__ out,
    float* __restrict__ part1) {
  constexpr int NST = (KDIM / BK) / KSPLIT;  // 64 (split) / 128 (fallback)
  __shared__ __align__(16) uint16_t As0[BM * BK];  // 32 KB each
  __shared__ __align__(16) uint16_t As1[BM * BK];
  __shared__ __align__(16) uint16_t Bs0[BN * BK];
  __shared__ __align__(16) uint16_t Bs1[BN * BK];

  const int tid = threadIdx.x;
  const int bid = blockIdx.x;

  int o0, ko, m_idx;
  if constexpr (KSPLIT == 2) {
    // bid&7 = XCD. Fix (o-half, ko) per XCD -> each XCD L2 holds its 4MB W2T
    // slice (2MB per ko) + 32 m-tiles of x. Bijective over (m 64, o 2, ko 2).
    const int g = bid & 7;
    o0 = (g >> 2) * BN;
    ko = g & 1;
    m_idx = (bid >> 3) * 2 + ((g >> 1) & 1);
  } else {
    o0 = (bid & 1) * BN;
    ko = 0;
    m_idx = bid >> 1;
  }
  const int m0 = m_idx * BM;
  const int kbase = ko * NST;  // global k-step offset

  const int wid = tid >> 6;   // 0..7
  const int lane = tid & 63;
  const int wm = wid >> 2;    // 0..1  wave m-slice (128 rows)
  const int wni = wid & 3;    // 0..3  wave n-slice (64 cols)
  const int q = lane >> 4;
  const int r = lane & 15;

  // A-staging: thread -> rows {ar+64i, i<4}, col-group ac (8 bf16 each)
  const int ar = tid >> 3;  // 0..63
  const int ac = tid & 7;   // 0..7
  const int awc = (ac ^ (ar & 7)) * 8;  // (ar+64i)&7 == ar&7
  // B-staging (global_load_lds: LDS dst = wave-uniform base + lane*16;
  // swizzle the GLOBAL col-group so fragment reads stay conflict-free)
  const int brow = lane >> 3;         // 0..7 within an 8-row chunk
  const int bcg = (lane & 7) ^ brow;  // swizzled col group

  const float* xrow[4];
#pragma unroll
  for (int i = 0; i < 4; ++i) xrow[i] = x + (size_t)(m0 + i * 64 + ar) * FDIM;

  f32x4 acc[8][4];
#pragma unroll
  for (int i = 0; i < 8; ++i)
#pragma unroll
    for (int j = 0; j < 4; ++j) acc[i][j] = {0.f, 0.f, 0.f, 0.f};

  auto preload = [&](RegSet& s, int kk) {
    const int ks = kbase + kk;
    const int fidx = ks >> 1;
    const int ho = ((ks & 1) << 6) + ac * 8;
    const float* wp = W1 + (size_t)fidx * HDIM + ho;
    const float* bp = b1 + (size_t)fidx * HDIM + ho;
    s.w1lo = *(const f32x4*)wp;
    s.w1hi = *(const f32x4*)(wp + 4);
    s.b1lo = *(const f32x4*)bp;
    s.b1hi = *(const f32x4*)(bp + 4);
#pragma unroll
    for (int i = 0; i < 4; ++i) s.xv[i] = xrow[i][fidx];
  };

  auto stageB = [&](uint16_t* Bb, int kk) {
    const int ks = kbase + kk;
#pragma unroll
    for (int j = 0; j < 4; ++j) {
      const int chunk = wid * 4 + j;  // 0..31, 1KB (8 rows x 64 cols) each
      const uint16_t* gp =
          W2T + (size_t)(o0 + chunk * 8 + brow) * KDIM + ks * BK + bcg * 8;
      uint16_t* lp = Bb + chunk * 512;  // wave-uniform base
      __builtin_amdgcn_global_load_lds(
          (const __attribute__((address_space(1))) uint32_t*)gp,
          (__attribute__((address_space(3))) uint32_t*)lp, 16, 0, 0);
    }
  };

  auto elu_write = [&](uint16_t* Ab, const RegSet& s) {
    float w[8], b[8];
#pragma unroll
    for (int p = 0; p < 4; ++p) {
      w[p] = s.w1lo[p]; w[p + 4] = s.w1hi[p];
      b[p] = s.b1lo[p]; b[p + 4] = s.b1hi[p];
    }
#pragma unroll
    for (int i = 0; i < 4; ++i) {
      u32x4 ov;
#pragma unroll
      for (int p = 0; p < 4; ++p) {
        float plo = fmaf(s.xv[i], w[2 * p], b[2 * p]);
        float phi = fmaf(s.xv[i], w[2 * p + 1], b[2 * p + 1]);
        // elu(p) = max(p, exp(min(p,0))-1): branch-free
        float elo = fmaxf(plo, __expf(fminf(plo, 0.f)) - 1.f);
        float ehi = fmaxf(phi, __expf(fminf(phi, 0.f)) - 1.f);
        ov[p] = __builtin_amdgcn_perm(__builtin_bit_cast(uint32_t, ehi),
                                      __builtin_bit_cast(uint32_t, elo),
                                      0x07060302u);
      }
      *(u32x4*)(Ab + (i * 64 + ar) * BK + awc) = ov;
    }
  };

  auto compute = [&](const uint16_t* Ab, const uint16_t* Bb) {
#pragma unroll
    for (int kc = 0; kc < 2; ++kc) {
      const int cg = kc * 4 + q;
      bf16x8 af[8], bfr[4];
#pragma unroll
      for (int mt = 0; mt < 8; ++mt) {
        const int row = wm * 128 + mt * 16 + r;
        af[mt] = *(const bf16x8*)&Ab[row * BK + ((cg ^ (row & 7)) * 8)];
      }
#pragma unroll
      for (int nt = 0; nt < 4; ++nt) {
        const int row = wni * 64 + nt * 16 + r;
        bfr[nt] = *(const bf16x8*)&Bb[row * BK + ((cg ^ (row & 7)) * 8)];
      }
#pragma unroll
      for (int mt = 0; mt < 8; ++mt)
#pragma unroll
        for (int nt = 0; nt < 4; ++nt)
          acc[mt][nt] = __builtin_amdgcn_mfma_f32_16x16x32_bf16(
              af[mt], bfr[nt], acc[mt][nt], 0, 0, 0);
    }
  };

  RegSet s0, s1;
  // prologue: regs(0) -> stage(0) -> regs(1)
  preload(s0, 0);
  stageB(Bs0, 0);
  preload(s1, 1);
  elu_write(As0, s0);
  __syncthreads();

#pragma unroll 1
  for (int kk = 0; kk < NST - 2; kk += 2) {
    // phase A: stage kk+1 -> buf1 (consumes s1), compute kk (buf0)
    preload(s0, kk + 2);
    stageB(Bs1, kk + 1);
    elu_write(As1, s1);
    compute(As0, Bs0);
    __syncthreads();
    // phase B: stage kk+2 -> buf0 (consumes s0), compute kk+1 (buf1)
    preload(s1, kk + 3);
    stageB(Bs0, kk + 2);
    elu_write(As0, s0);
    compute(As1, Bs1);
    __syncthreads();
  }
  // tail: stage NST-1 -> buf1 (consumes s1), compute NST-2, NST-1
  stageB(Bs1, NST - 1);
  elu_write(As1, s1);
  compute(As0, Bs0);
  __syncthreads();
  compute(As1, Bs1);

  // ---- epilogue ----
  if constexpr (KSPLIT == 2) {
    // raw partial: ko=0 -> out, ko=1 -> part1 (combine adds b2sum & scales)
    float* P = ko ? part1 : out;
#pragma unroll
    for (int mt = 0; mt < 8; ++mt)
#pragma unroll
      for (int nt = 0; nt < 4; ++nt)
#pragma unroll
        for (int v = 0; v < 4; ++v) {
          const int row = m0 + wm * 128 + mt * 16 + q * 4 + v;
          const int col = o0 + wni * 64 + nt * 16 + r;
          P[(size_t)row * ODIM + col] = acc[mt][nt][v];
        }
  } else {
    float bsv[4];
#pragma unroll
    for (int nt = 0; nt < 4; ++nt) bsv[nt] = b2sum[o0 + wni * 64 + nt * 16 + r];
#pragma unroll
    for (int mt = 0; mt < 8; ++mt)
#pragma unroll
      for (int nt = 0; nt < 4; ++nt)
#pragma unroll
        for (int v = 0; v < 4; ++v) {
          const int row = m0 + wm * 128 + mt * 16 + q * 4 + v;
          const int col = o0 + wni * 64 + nt * 16 + r;
          out[(size_t)row * ODIM + col] = (acc[mt][nt][v] + bsv[nt]) * 0.125f;
        }
  }
}

extern "C" void kernel_launch(void* const* d_in, const int* in_sizes, int n_in,
                              void* d_out, int out_size, void* d_ws, size_t ws_size,
                              hipStream_t stream) {
  const float* x  = (const float*)d_in[0];
  const float* W1 = (const float*)d_in[1];
  const float* b1 = (const float*)d_in[2];
  const float* W2 = (const float*)d_in[3];
  const float* b2 = (const float*)d_in[4];
  float* out = (float*)d_out;

  char* ws = (char*)d_ws;
  const size_t W2T_OFF = 65536;
  const size_t P1_OFF = W2T_OFF + (size_t)ODIM * KDIM * 2;       // 8454144
  const size_t NEED = P1_OFF + (size_t)NROWS * ODIM * 4;         // +32 MB
  float*    b2sum = (float*)ws;
  uint16_t* W2T   = (uint16_t*)(ws + W2T_OFF);
  float*    part1 = (float*)(ws + P1_OFF);

  prep_w2t<<<dim3(KDIM / 64, ODIM / 64), dim3(64, 8), 0, stream>>>(W2, W2T);
  prep_b2sum<<<2, 256, 0, stream>>>(b2, b2sum);

  if (ws_size >= NEED) {
    mlp_gemm<2><<<256, 512, 0, stream>>>(x, W1, b1, W2T, b2sum, out, part1);
    combine_out<<<(NROWS * ODIM) / 1024, 256, 0, stream>>>(part1, b2sum, out);
  } else {
    mlp_gemm<1><<<128, 512, 0, stream>>>(x, W1, b1, W2T, b2sum, out, nullptr);
  }
}